// Round 16
// baseline (201.062 us; speedup 1.0000x reference)
//
#include <hip/hip_runtime.h>
#include <stdint.h>

#define TOKENS 8192
#define IN_F   4096
#define OUT_F  4096

#define BM 256
#define BN 256
#define BK 64                 // bytes of K per slice (64 int8)
#define NK (IN_F / BK)        // 64 slices
#define THREADS 1024

typedef int v4i  __attribute__((ext_vector_type(4)));
typedef int v16i __attribute__((ext_vector_type(16)));

#define GLOBAL_AS __attribute__((address_space(1)))
#define LDS_AS    __attribute__((address_space(3)))

// ---- fused pack: x int32->int8, W int32 [K][N] -> int8 WT [N][K] ----
#define XBLOCKS (TOKENS * IN_F / 4 / 256)   // 8192
__global__ __launch_bounds__(256) void pack_kernel(const int* __restrict__ x32,
                                                   uint8_t* __restrict__ x8,
                                                   const int* __restrict__ w32,
                                                   uint8_t* __restrict__ wt8) {
  if (blockIdx.x < XBLOCKS) {
    int t = blockIdx.x * 256 + threadIdx.x;
    const int4 v = ((const int4*)x32)[t];
    uint32_t p = (uint32_t)(v.x & 0xFF)
               | ((uint32_t)(v.y & 0xFF) << 8)
               | ((uint32_t)(v.z & 0xFF) << 16)
               | ((uint32_t)(v.w & 0xFF) << 24);
    ((uint32_t*)x8)[t] = p;
  } else {
    int b = blockIdx.x - XBLOCKS;
    int tn = (b & 63) * 64;
    int tk = (b >> 6) * 64;
    int t = threadIdx.x;
    int n  = tn + (t >> 2);
    int k0 = tk + (t & 3) * 16;
    uint32_t words[4];
#pragma unroll
    for (int w = 0; w < 4; ++w) {
      uint32_t acc = 0;
#pragma unroll
      for (int j = 0; j < 4; ++j) {
        int val = w32[(size_t)(k0 + w * 4 + j) * OUT_F + n];
        acc |= (uint32_t)(val & 0xFF) << (8 * j);
      }
      words[w] = acc;
    }
    uint4 o = make_uint4(words[0], words[1], words[2], words[3]);
    *(uint4*)(wt8 + (size_t)n * IN_F + k0) = o;
  }
}

// ---- int8 GEMM: R9 structure (best, 95% of 16x16 ceiling) on the 12%-faster
// ---- mfma_i32_32x32x32_i8 shape. 16 waves (4m x 4n), wave tile 64x64 =
// ---- 2x2 tiles of 32x32 (acc 2x2x16 = 64 regs, same budget as R9).
// Operand layout (32x32x32): lane l supplies row/col l&31, k-bytes
// (l>>5)*16..+16 per 32-k step. C/D: col=l&31, row=(reg&3)+8*(reg>>2)+4*(l>>5).
__global__ __launch_bounds__(THREADS, 4) void gemm_i8_kernel(const uint8_t* __restrict__ A,
                                                             const uint8_t* __restrict__ BT,
                                                             const int* __restrict__ bias,
                                                             const float* __restrict__ scales,
                                                             int* __restrict__ out) {
  __shared__ __align__(16) uint8_t lds[4 * 32768];   // ring of 4 slices, 128 KiB

  const int t    = threadIdx.x;
  const int lane = t & 63;
  const int w    = t >> 6;     // 0..15
  const int wm   = w >> 2;     // 0..3
  const int wn   = w & 3;      // 0..3
  const int fr   = lane & 31;  // row/col within 32x32 tile
  const int hi   = lane >> 5;  // k-chunk selector

  // XCD-aware bijective swizzle: 512 blocks, 512 % 8 == 0
  int bid = blockIdx.x;
  int swz = (bid & 7) * 64 + (bid >> 3);
  int bm = swz >> 4;           // 0..31
  int bn = swz & 15;           // 0..15

  // staging: pre-swizzled global source, linear LDS dest (rule #21).
  // sigma(l)=l^((l>>3)&7) on 16B chunks per 8-KiB half (0-conflict R3-R15);
  // byte form: phys = (row*64 + c*16) ^ (((row>>1)&7)<<4), row-only -> the
  // read-side XOR carries over verbatim for any 16B-aligned k-offset.
  const int half = t >> 9;
  const int tt   = t & 511;
  const int lsz  = tt ^ ((tt >> 3) & 7);
  const int srow = half * 128 + (lsz >> 2);   // 0..255
  const int scol = (lsz & 3) * 16;
  const size_t gA = (size_t)(bm * BM + srow) * IN_F + scol;
  const size_t gB = (size_t)(bn * BN + srow) * IN_F + scol;
  const int ldst = half * 8192 + tt * 16;

  auto stage = [&](int j) {            // 2 loads per thread per slice
    uint8_t* sb = lds + (j & 3) * 32768;
    const int k0 = j * BK;
    __builtin_amdgcn_global_load_lds((const GLOBAL_AS void*)(A + gA + k0),
                                     (LDS_AS void*)(sb + ldst),          16, 0, 0);
    __builtin_amdgcn_global_load_lds((const GLOBAL_AS void*)(BT + gB + k0),
                                     (LDS_AS void*)(sb + 16384 + ldst),  16, 0, 0);
  };

  // fragment read offsets: tile mt/nt (0..1), k-step ks (0..1).
  // addr = hh*8192 + (rl*64 + ks*32 + hi*16) ^ (((rl>>1)&7)<<4)
  int aoff[2][2], boff[2][2];
#pragma unroll
  for (int mt = 0; mt < 2; ++mt) {
    int row = wm * 64 + mt * 32 + fr;       // 0..255
    int hh = row >> 7, rl = row & 127;
    int sig = ((rl >> 1) & 7) << 4;
#pragma unroll
    for (int ks = 0; ks < 2; ++ks)
      aoff[mt][ks] = hh * 8192 + ((rl * 64 + ks * 32 + hi * 16) ^ sig);
  }
#pragma unroll
  for (int nt = 0; nt < 2; ++nt) {
    int row = wn * 64 + nt * 32 + fr;       // 0..255
    int hh = row >> 7, rl = row & 127;
    int sig = ((rl >> 1) & 7) << 4;
#pragma unroll
    for (int ks = 0; ks < 2; ++ks)
      boff[nt][ks] = 16384 + hh * 8192 + ((rl * 64 + ks * 32 + hi * 16) ^ sig);
  }

  v16i acc[2][2];
#pragma unroll
  for (int mt = 0; mt < 2; ++mt)
#pragma unroll
    for (int nt = 0; nt < 2; ++nt)
#pragma unroll
      for (int r = 0; r < 16; ++r) acc[mt][nt][r] = 0;

  // Prologue: fill 3 slots (6 loads/thread in flight).
  stage(0); stage(1); stage(2);

  // ITER(i): vmcnt(VM) -> slice i landed (i+1,i+2 in flight; never 0 mid-loop);
  // barrier; stage(i+3) -> slot (i-1)&3 whose readers drained via MFMA data
  // deps before this barrier; 8x ds_read_b128; 8 MFMA 32x32x32 (compiler-
  // counted lgkm, no pin) with setprio. R9-proven structure.
#define ITER(i, VM, DOSTAGE)                                                    \
  {                                                                             \
    asm volatile("s_waitcnt vmcnt(" #VM ")" ::: "memory");                      \
    asm volatile("s_barrier" ::: "memory");                                     \
    if (DOSTAGE) stage((i) + 3);                                                \
    const uint8_t* sb = lds + ((i) & 3) * 32768;                                \
    v4i af[2][2], bf[2][2];                                                     \
    _Pragma("unroll") for (int mt = 0; mt < 2; ++mt)                            \
      _Pragma("unroll") for (int ks = 0; ks < 2; ++ks)                          \
        af[mt][ks] = *(const v4i*)(sb + aoff[mt][ks]);                          \
    _Pragma("unroll") for (int nt = 0; nt < 2; ++nt)                            \
      _Pragma("unroll") for (int ks = 0; ks < 2; ++ks)                          \
        bf[nt][ks] = *(const v4i*)(sb + boff[nt][ks]);                          \
    __builtin_amdgcn_s_setprio(1);                                              \
    _Pragma("unroll") for (int ks = 0; ks < 2; ++ks)                            \
      _Pragma("unroll") for (int mt = 0; mt < 2; ++mt)                          \
        _Pragma("unroll") for (int nt = 0; nt < 2; ++nt)                        \
          acc[mt][nt] = __builtin_amdgcn_mfma_i32_32x32x32_i8(                  \
              af[mt][ks], bf[nt][ks], acc[mt][nt], 0, 0, 0);                    \
    __builtin_amdgcn_s_setprio(0);                                              \
  }

  for (int i = 0; i < NK - 3; ++i) {
    ITER(i, 4, true)
  }
  ITER(NK - 3, 4, false)
  ITER(NK - 2, 2, false)
  ITER(NK - 1, 0, false)
#undef ITER

  // ---- epilogue: (acc + bias) * scale * 20, clip, trunc; int32 out ----
  // C/D layout (32x32): col = lane&31, row = (reg&3) + 8*(reg>>2) + 4*(lane>>5)
#pragma unroll
  for (int nt = 0; nt < 2; ++nt) {
    const int gn  = bn * BN + wn * 64 + nt * 32 + fr;
    const int bsv = bias[gn];
    const float sc = scales[gn] * 20.0f;
#pragma unroll
    for (int mt = 0; mt < 2; ++mt) {
      const int gm0 = bm * BM + wm * 64 + mt * 32 + hi * 4;
#pragma unroll
      for (int r = 0; r < 16; ++r) {
        const int gm = gm0 + (r & 3) + 8 * (r >> 2);
        float g = (float)(acc[mt][nt][r] + bsv) * sc;
        g = fminf(fmaxf(g, -128.0f), 127.0f);
        out[(size_t)gm * OUT_F + gn] = (int)g;
      }
    }
  }
}

extern "C" void kernel_launch(void* const* d_in, const int* in_sizes, int n_in,
                              void* d_out, int out_size, void* d_ws, size_t ws_size,
                              hipStream_t stream) {
  const int*   x32    = (const int*)d_in[0];
  const int*   w32    = (const int*)d_in[1];
  const int*   bias   = (const int*)d_in[2];
  const float* scales = (const float*)d_in[3];
  int* out = (int*)d_out;

  uint8_t* x8  = (uint8_t*)d_ws;                              // 32 MB
  uint8_t* wt8 = (uint8_t*)d_ws + (size_t)TOKENS * IN_F;      // 16 MB

  pack_kernel<<<XBLOCKS + (OUT_F / 64) * (IN_F / 64), 256, 0, stream>>>(x32, x8, w32, wt8);
  gemm_i8_kernel<<<(TOKENS / BM) * (OUT_F / BN), THREADS, 0, stream>>>(x8, wt8, bias, scales, out);
}

// Round 17
// 186.881 us; speedup vs baseline: 1.0759x; 1.0759x over previous
//
#include <hip/hip_runtime.h>
#include <stdint.h>

#define TOKENS 8192
#define IN_F   4096
#define OUT_F  4096

#define BM 256
#define BN 256
#define BK 64                 // bytes of K per slice (64 int8)
#define NK (IN_F / BK)        // 64 slices
#define THREADS 1024

typedef int v4i __attribute__((ext_vector_type(4)));

#define GLOBAL_AS __attribute__((address_space(1)))
#define LDS_AS    __attribute__((address_space(3)))

// ---- fused pack: x int32->int8, W int32 [K][N] -> int8 WT [N][K] ----
// (R14 version: single launch, ~30us, at the HBM/L3 floor for 240 MB moved)
#define XBLOCKS (TOKENS * IN_F / 4 / 256)   // 8192
__global__ __launch_bounds__(256) void pack_kernel(const int* __restrict__ x32,
                                                   uint8_t* __restrict__ x8,
                                                   const int* __restrict__ w32,
                                                   uint8_t* __restrict__ wt8) {
  if (blockIdx.x < XBLOCKS) {
    int t = blockIdx.x * 256 + threadIdx.x;
    const int4 v = ((const int4*)x32)[t];
    uint32_t p = (uint32_t)(v.x & 0xFF)
               | ((uint32_t)(v.y & 0xFF) << 8)
               | ((uint32_t)(v.z & 0xFF) << 16)
               | ((uint32_t)(v.w & 0xFF) << 24);
    ((uint32_t*)x8)[t] = p;
  } else {
    int b = blockIdx.x - XBLOCKS;
    int tn = (b & 63) * 64;
    int tk = (b >> 6) * 64;
    int t = threadIdx.x;
    int n  = tn + (t >> 2);
    int k0 = tk + (t & 3) * 16;
    uint32_t words[4];
#pragma unroll
    for (int w = 0; w < 4; ++w) {
      uint32_t acc = 0;
#pragma unroll
      for (int j = 0; j < 4; ++j) {
        int val = w32[(size_t)(k0 + w * 4 + j) * OUT_F + n];
        acc |= (uint32_t)(val & 0xFF) << (8 * j);
      }
      words[w] = acc;
    }
    uint4 o = make_uint4(words[0], words[1], words[2], words[3]);
    *(uint4*)(wt8 + (size_t)n * IN_F + k0) = o;
  }
}

// ---- int8 GEMM: R9 verbatim (best measured: 147us, 95% of the 16x16x64
// ---- i8 ceiling; 0 bank conflicts; no lgkm pin; ring-4; counted vmcnt) ----
__global__ __launch_bounds__(THREADS, 4) void gemm_i8_kernel(const uint8_t* __restrict__ A,
                                                             const uint8_t* __restrict__ BT,
                                                             const int* __restrict__ bias,
                                                             const float* __restrict__ scales,
                                                             int* __restrict__ out) {
  __shared__ __align__(16) uint8_t lds[4 * 32768];   // ring of 4 slices, 128 KiB

  const int t    = threadIdx.x;
  const int lane = t & 63;
  const int w    = t >> 6;     // 0..15
  const int wm   = w >> 2;     // 0..3
  const int wn   = w & 3;      // 0..3
  const int fr   = lane & 15;
  const int fq   = lane >> 4;

  // XCD-aware bijective swizzle: 512 blocks, 512 % 8 == 0
  int bid = blockIdx.x;
  int swz = (bid & 7) * 64 + (bid >> 3);
  int bm = swz >> 4;           // 0..31
  int bn = swz & 15;           // 0..15

  // staging: pre-swizzled global source, linear LDS dest (rule #21).
  // sigma(l)=l^((l>>3)&7) on 16B chunks per 8-KiB half (0-conflict R3-R15
  // for the 16x16 quarter-wave read pattern).
  const int half = t >> 9;
  const int tt   = t & 511;
  const int lsz  = tt ^ ((tt >> 3) & 7);
  const int srow = half * 128 + (lsz >> 2);   // 0..255
  const int scol = (lsz & 3) * 16;
  const size_t gA = (size_t)(bm * BM + srow) * IN_F + scol;
  const size_t gB = (size_t)(bn * BN + srow) * IN_F + scol;
  const int ldst = half * 8192 + tt * 16;

  auto stage = [&](int j) {            // 2 loads per thread per slice
    uint8_t* sb = lds + (j & 3) * 32768;
    const int k0 = j * BK;
    __builtin_amdgcn_global_load_lds((const GLOBAL_AS void*)(A + gA + k0),
                                     (LDS_AS void*)(sb + ldst),          16, 0, 0);
    __builtin_amdgcn_global_load_lds((const GLOBAL_AS void*)(BT + gB + k0),
                                     (LDS_AS void*)(sb + 16384 + ldst),  16, 0, 0);
  };

  // fragment read offsets (slot-relative), sigma-swizzled to match staging
  int aoff[4], boff[4];
#pragma unroll
  for (int m = 0; m < 4; ++m) {
    int row = wm * 64 + m * 16 + fr;        // 0..255
    int hh = row >> 7, rl = row & 127;
    int b = rl * 64 + fq * 16;
    b ^= ((rl >> 1) & 7) << 4;
    aoff[m] = hh * 8192 + b;
  }
#pragma unroll
  for (int n = 0; n < 4; ++n) {
    int row = wn * 64 + n * 16 + fr;        // 0..255
    int hh = row >> 7, rl = row & 127;
    int b = rl * 64 + fq * 16;
    b ^= ((rl >> 1) & 7) << 4;
    boff[n] = 16384 + hh * 8192 + b;
  }

  v4i acc[4][4];
  const v4i vzero = {0, 0, 0, 0};
#pragma unroll
  for (int m = 0; m < 4; ++m)
#pragma unroll
    for (int n = 0; n < 4; ++n) acc[m][n] = vzero;

  // Prologue: fill 3 slots (6 loads/thread in flight).
  stage(0); stage(1); stage(2);

  // ITER(i): vmcnt(VM) -> slice i landed (i+1,i+2 in flight; never 0 mid-loop);
  // barrier; stage(i+3) -> slot (i-1)&3 whose readers drained via MFMA data
  // deps before this barrier; 8x ds_read_b128; 16 MFMA with compiler-counted
  // lgkm (no pin) under setprio.
#define ITER(i, VM, DOSTAGE)                                                    \
  {                                                                             \
    asm volatile("s_waitcnt vmcnt(" #VM ")" ::: "memory");                      \
    asm volatile("s_barrier" ::: "memory");                                     \
    if (DOSTAGE) stage((i) + 3);                                                \
    const uint8_t* sb = lds + ((i) & 3) * 32768;                                \
    v4i af[4], bf[4];                                                           \
    _Pragma("unroll") for (int m = 0; m < 4; ++m)                               \
      af[m] = *(const v4i*)(sb + aoff[m]);                                      \
    _Pragma("unroll") for (int n = 0; n < 4; ++n)                               \
      bf[n] = *(const v4i*)(sb + boff[n]);                                      \
    __builtin_amdgcn_s_setprio(1);                                              \
    _Pragma("unroll") for (int m = 0; m < 4; ++m)                               \
      _Pragma("unroll") for (int n = 0; n < 4; ++n)                             \
        acc[m][n] = __builtin_amdgcn_mfma_i32_16x16x64_i8(af[m], bf[n],         \
                                                          acc[m][n], 0, 0, 0);  \
    __builtin_amdgcn_s_setprio(0);                                              \
  }

  for (int i = 0; i < NK - 3; ++i) {
    ITER(i, 4, true)
  }
  ITER(NK - 3, 4, false)
  ITER(NK - 2, 2, false)
  ITER(NK - 1, 0, false)
#undef ITER

  // ---- epilogue: (acc + bias) * scale * 20, clip, trunc; int32 out ----
  // C/D layout (16x16): col = lane&15, row = (lane>>4)*4 + r
#pragma unroll
  for (int n = 0; n < 4; ++n) {
    const int gn  = bn * BN + wn * 64 + n * 16 + fr;
    const int bsv = bias[gn];
    const float sc = scales[gn] * 20.0f;
#pragma unroll
    for (int m = 0; m < 4; ++m) {
      const int gm0 = bm * BM + wm * 64 + m * 16 + fq * 4;
#pragma unroll
      for (int r = 0; r < 4; ++r) {
        float g = (float)(acc[m][n][r] + bsv) * sc;
        g = fminf(fmaxf(g, -128.0f), 127.0f);
        out[(size_t)(gm0 + r) * OUT_F + gn] = (int)g;
      }
    }
  }
}

extern "C" void kernel_launch(void* const* d_in, const int* in_sizes, int n_in,
                              void* d_out, int out_size, void* d_ws, size_t ws_size,
                              hipStream_t stream) {
  const int*   x32    = (const int*)d_in[0];
  const int*   w32    = (const int*)d_in[1];
  const int*   bias   = (const int*)d_in[2];
  const float* scales = (const float*)d_in[3];
  int* out = (int*)d_out;

  uint8_t* x8  = (uint8_t*)d_ws;                              // 32 MB
  uint8_t* wt8 = (uint8_t*)d_ws + (size_t)TOKENS * IN_F;      // 16 MB

  pack_kernel<<<XBLOCKS + (OUT_F / 64) * (IN_F / 64), 256, 0, stream>>>(x32, x8, w32, wt8);
  gemm_i8_kernel<<<(TOKENS / BM) * (OUT_F / BN), THREADS, 0, stream>>>(x8, wt8, bias, scales, out);
}